// Round 13
// baseline (267.504 us; speedup 1.0000x reference)
//
#include <hip/hip_runtime.h>
#include <stdint.h>

#define NB 4
#define KTOT 5480
#define PER_IMG 258720
#define SCORE_THR 0.02f
#define IOU_THR 0.45f
#define REL_BASE 0x3CA3D70Bu   // smallest float bits > 0.02f
#define ICH2 22                // rankdec i-chunks (256 keys each)
#define NMSCAP 512
#define HBINS 256              // coarse hist bins: (kb-REL_BASE)>>18 in [0,182]
#define HPART 42               // max partials per task (lev0)

__constant__ int cFEAT[6]    = {20,10,5,3,2,1};
__constant__ int cSTRIDE[6]  = {16,32,64,107,160,320};
__constant__ int cMIN[6]     = {48,100,150,202,253,304};
__constant__ int cMAX[6]     = {100,150,202,253,304,320};
__constant__ int cNFLAT[6]   = {192000,48000,12000,4320,1920,480};
__constant__ int cFLATOFF[6] = {0,192000,240000,252000,256320,258240};
__constant__ int cKSEL[6]    = {1000,1000,1000,1000,1000,480};
__constant__ int cKOFF[6]    = {0,1000,2000,3000,4000,5000};
__constant__ double cRATIO[6] = {1.0,1.0,0.5,2.0,1.0/3.0,3.0};
// emit entries: 16 lev0 chunks, 4 lev1 chunks, 1 each lev2..5 -> 24 per image
__constant__ int eTLEV[24] = {0,0,0,0,0,0,0,0,0,0,0,0,0,0,0,0, 1,1,1,1, 2,3,4,5};
__constant__ int eTCHK[24] = {0,1,2,3,4,5,6,7,8,9,10,11,12,13,14,15, 0,1,2,3, 0,0,0,0};
__constant__ int eNCH[6]   = {16,4,1,1,1,1};
__constant__ int hL0[6]    = {0,42,54,60,66,72};   // softmax-block range per level
__constant__ int hLN[6]    = {42,12,6,6,6,6};

__device__ __forceinline__ unsigned long long mk_key(unsigned kb, int lev, unsigned idx) {
  return ((unsigned long long)kb << 21) |
         (unsigned long long)(0x1FFFFFu ^ (((unsigned)lev << 18) | idx));
}

__device__ __forceinline__ unsigned long long shfl64(unsigned long long x, int src) {
  int lo = __shfl((int)(unsigned)(x & 0xffffffffull), src);
  int hi = __shfl((int)(unsigned)(x >> 32), src);
  return ((unsigned long long)(unsigned)hi << 32) | (unsigned)lo;
}

// ---------------- K1: tiled softmax + per-block overwrite histogram --------------
// bhist layout is BIN-MAJOR: bhist[(task*HBINS + bin)*HPART + j].
__global__ __launch_bounds__(256) void k_softmax(
    const float* __restrict__ c0, const float* __restrict__ c1,
    const float* __restrict__ c2, const float* __restrict__ c3,
    const float* __restrict__ c4, const float* __restrict__ c5,
    float* __restrict__ scores, unsigned* __restrict__ bhist,
    unsigned* __restrict__ obmax_u, unsigned* __restrict__ ctrl)
{
  int t = blockIdx.x;
  int tid = threadIdx.x;
  if (t == 0) {
    if (tid < 4) obmax_u[tid] = 0u;
    if (tid >= 64 && tid < 256) ctrl[tid - 64] = 0u;
  }
  int b = t / 78, rem = t % 78;
  int lev, a, cb;
  if (rem < 42)      { lev = 0; a = rem / 7;         cb = (rem % 7) * 64; }
  else if (rem < 54) { lev = 1; a = (rem - 42) >> 1; cb = ((rem - 42) & 1) * 64; }
  else               { lev = 2 + (rem - 54) / 6; a = (rem - 54) % 6; cb = 0; }
  const float* cls = (lev==0)?c0:(lev==1)?c1:(lev==2)?c2:(lev==3)?c3:(lev==4)?c4:c5;
  int f = cFEAT[lev], ff = f * f;
  int ncell = ff - cb; if (ncell > 64) ncell = 64;

  __shared__ float tile[81 * 64];
  __shared__ unsigned hcnt[HBINS];
  if (tid < HBINS) hcnt[tid] = 0;
  const float* base = cls + (size_t)(b * 486 + a * 81) * ff + cb;
  for (int t2 = tid; t2 < 81 * 64; t2 += 256) {
    int c = t2 >> 6, cell = t2 & 63;
    if (cell < ncell)
      tile[(c << 6) | (cell ^ (c & 63))] = base[c * ff + cell];
  }
  __syncthreads();

  int lane = tid & 63, w = tid >> 6;
  for (int cell = w; cell < ncell; cell += 4) {
    float v1 = tile[(lane << 6) | (cell ^ lane)];
    float v2 = (lane <= 16) ? tile[((lane + 64) << 6) | (cell ^ lane)]
                            : __uint_as_float(0xff800000u);
    float mx = fmaxf(v1, v2);
    #pragma unroll
    for (int m = 32; m; m >>= 1) mx = fmaxf(mx, __shfl_xor(mx, m));
    float e1 = expf(v1 - mx);
    float e2 = (lane <= 16) ? expf(v2 - mx) : 0.f;
    float sm = e1 + e2;
    #pragma unroll
    for (int m = 32; m; m >>= 1) sm += __shfl_xor(sm, m);
    int row = (cb + cell) * 6 + a;
    float* out = scores + (size_t)b * PER_IMG + cFLATOFF[lev] + row * 80;
    float p1 = e1 / sm;
    out[lane] = (p1 > SCORE_THR) ? p1 : -1.f;
    if (p1 > SCORE_THR)
      atomicAdd(&hcnt[(__float_as_uint(p1) - REL_BASE) >> 18], 1u);
    if (lane < 16) {
      float p2 = e2 / sm;
      out[lane + 64] = (p2 > SCORE_THR) ? p2 : -1.f;
      if (p2 > SCORE_THR)
        atomicAdd(&hcnt[(__float_as_uint(p2) - REL_BASE) >> 18], 1u);
    }
  }
  __syncthreads();
  int task = b * 6 + lev;
  int j = rem - hL0[lev];
  if (tid < HBINS)
    bhist[((size_t)task * HBINS + tid) * HPART + j] = hcnt[tid];
}

// ---------------- K2: chunked emit with inline plan (bin-major hist sum) ---------
__global__ __launch_bounds__(256) void k_emit(
    const float* __restrict__ scores, const unsigned* __restrict__ bhist,
    unsigned* __restrict__ ctrl, unsigned long long* __restrict__ selkeys,
    unsigned long long* __restrict__ eqg)
{
  int b = blockIdx.x / 24, ent = blockIdx.x % 24;
  int lev = eTLEV[ent], chk = eTCHK[ent];
  int task = b * 6 + lev;
  int n = cNFLAT[lev];
  int tid = threadIdx.x;
  const float* s = scores + (size_t)b * PER_IMG + cFLATOFF[lev];
  unsigned long long* out = selkeys + (size_t)b * KTOT + cKOFF[lev];

  if (lev == 5) {  // keep all
    for (int i = tid; i < n; i += 256) {
      float v = s[i];
      unsigned kb = (v > SCORE_THR) ? __float_as_uint(v) : 0u;
      out[i] = mk_key(kb, lev, (unsigned)i);
    }
    return;
  }

  unsigned k = (unsigned)cKSEL[lev];
  __shared__ unsigned long long wbuf[1024];
  __shared__ unsigned long long ebuf[4096];
  __shared__ unsigned sc[256];
  __shared__ unsigned wcnt, ecnt, sbw, sbe, sh_mode, sh_b1;

  // ---- inline plan: bin-major sum (contiguous), suffix-scan 256 bins ----
  {
    const unsigned* hb = bhist + ((size_t)task * HBINS + tid) * HPART;
    int np = hLN[lev];
    unsigned cnt = 0;
    for (int j = 0; j < np; ++j) cnt += hb[j];   // contiguous: ~3 cache lines
    sc[tid] = cnt;
    __syncthreads();
    for (int off = 1; off < 256; off <<= 1) {
      unsigned cur = sc[tid];
      unsigned add = (tid + off < 256) ? sc[tid + off] : 0u;
      __syncthreads();
      sc[tid] = cur + add;
      __syncthreads();
    }
    unsigned c = sc[0];
    if (tid == 0 && c < k) sh_mode = 1u;
    if (c >= k) {
      unsigned above = (tid == 255) ? 0u : sc[tid + 1];
      if (above < k && above + cnt >= k) { sh_mode = 0u; sh_b1 = (unsigned)tid; }
    }
    if (tid == 0) { wcnt = 0; ecnt = 0; }
    __syncthreads();
  }
  unsigned mode = sh_mode;

  int csz = n / eNCH[lev];
  int start = chk * csz;
  const float4* s4 = (const float4*)(s + start);
  int n4 = csz >> 2;

  if (mode == 0u) {
    unsigned b1 = sh_b1;
    unsigned base_lo = REL_BASE + (b1 << 18);
    unsigned base_hi = base_lo + (1u << 18);
    #pragma unroll 4
    for (int i0 = tid; i0 < n4; i0 += 256) {
      float4 vv = s4[i0];
      #pragma unroll
      for (int e2 = 0; e2 < 4; ++e2) {
        float v = (e2==0)?vv.x:(e2==1)?vv.y:(e2==2)?vv.z:vv.w;
        if (v > SCORE_THR) {
          unsigned kb = __float_as_uint(v);
          unsigned idx = (unsigned)(start + i0 * 4 + e2);
          if (kb >= base_hi) {
            unsigned p = atomicAdd(&wcnt, 1u);
            if (p < 1024u) wbuf[p] = mk_key(kb, lev, idx);
          } else if (kb >= base_lo) {
            unsigned p = atomicAdd(&ecnt, 1u);
            if (p < 4096u) ebuf[p] = mk_key(kb, lev, idx);
          }
        }
      }
    }
  } else {  // mode 1: all candidates are winners (c < k)
    #pragma unroll 4
    for (int i0 = tid; i0 < n4; i0 += 256) {
      float4 vv = s4[i0];
      #pragma unroll
      for (int e2 = 0; e2 < 4; ++e2) {
        float v = (e2==0)?vv.x:(e2==1)?vv.y:(e2==2)?vv.z:vv.w;
        if (v > SCORE_THR) {
          unsigned p = atomicAdd(&wcnt, 1u);
          if (p < 1024u) wbuf[p] = mk_key(__float_as_uint(v), lev,
                                          (unsigned)(start + i0 * 4 + e2));
        }
      }
    }
  }
  __syncthreads();
  if (tid == 0) {
    sbw = atomicAdd(&ctrl[task * 8 + 2], wcnt);
    sbe = atomicAdd(&ctrl[task * 8 + 3], ecnt);
  }
  __syncthreads();
  unsigned nw = (wcnt < 1024u) ? wcnt : 1024u;
  unsigned ne = (ecnt < 4096u) ? ecnt : 4096u;
  unsigned bw = sbw, be = sbe;
  for (unsigned t = tid; t < nw; t += 256) out[bw + t] = wbuf[t];
  for (unsigned t = tid; t < ne; t += 256) {
    unsigned g = be + t;
    if (g < 4096u) eqg[(size_t)task * 4096 + g] = ebuf[t];
  }
}

// ---------------- K3: finalize (ties / fillers / pathological radix) -------------
__global__ __launch_bounds__(1024) void k_finalize(
    const float* __restrict__ scores, const unsigned* __restrict__ bhist,
    const unsigned* __restrict__ ctrl, unsigned long long* __restrict__ selkeys,
    const unsigned long long* __restrict__ eqg)
{
  int task = blockIdx.x;
  int b = task / 6, lev = task % 6;
  if (lev == 5) return;
  int tid = threadIdx.x;
  unsigned k = (unsigned)cKSEL[lev];
  int n = cNFLAT[lev];
  const float* s = scores + (size_t)b * PER_IMG + cFLATOFF[lev];
  unsigned long long* out = selkeys + (size_t)b * KTOT + cKOFF[lev];
  unsigned levtag = (unsigned)lev << 18;

  __shared__ unsigned long long eqb[4096];
  __shared__ unsigned sc[1024];
  __shared__ unsigned sh_cnt, sh_eq, sh_byte, sh_r;

  // ---- recompute candidate count from bin-major partials ----
  unsigned hval = 0;
  if (tid < HBINS) {
    const unsigned* hb = bhist + ((size_t)task * HBINS + tid) * HPART;
    int np = hLN[lev];
    for (int j = 0; j < np; ++j) hval += hb[j];
  }
  sc[tid] = (tid < HBINS) ? hval : 0u;
  __syncthreads();
  for (int off = 128; off >= 1; off >>= 1) {
    if (tid < off) sc[tid] += sc[tid + off];
    __syncthreads();
  }
  unsigned c = sc[0];
  __syncthreads();
  unsigned mode = (c >= k) ? 0u : 1u;
  bool done = false;

  if (mode == 0u) {
    unsigned cnt = ctrl[task * 8 + 2];
    unsigned e = ctrl[task * 8 + 3];
    unsigned need = k - cnt;
    if (e <= 4096u) {
      const unsigned long long* eq = eqg + (size_t)task * 4096;
      if (e == need) {
        for (unsigned t = tid; t < need; t += 1024) out[cnt + t] = eq[t];
      } else {
        unsigned P = 1; while (P < e) P <<= 1;
        for (unsigned t = tid; t < P; t += 1024) eqb[t] = (t < e) ? eq[t] : 0ull;
        __syncthreads();
        for (unsigned sz = 2; sz <= P; sz <<= 1)
          for (unsigned st = sz >> 1; st; st >>= 1) {
            for (unsigned w = tid; w < P / 2; w += 1024) {
              unsigned i = ((w & ~(st - 1)) << 1) | (w & (st - 1));
              unsigned l = i | st;
              bool up = ((i & sz) == 0);
              unsigned long long A = eqb[i], B = eqb[l];
              if ((A < B) == up) { eqb[i] = B; eqb[l] = A; }  // descending
            }
            __syncthreads();
          }
        for (unsigned t = tid; t < need; t += 1024) out[cnt + t] = eqb[t];
      }
      done = true;
    }
  } else {
    // mode 1: candidates already emitted; append (k-c) smallest-index fillers
    unsigned c2 = ctrl[task * 8 + 2];
    unsigned need = k - c2;
    unsigned base = 0;
    for (int start = 0; start < n && base < need; start += 1024) {
      int i = start + tid;
      unsigned pred = (i < n && !(s[i] > SCORE_THR)) ? 1u : 0u;
      sc[tid] = pred;
      __syncthreads();
      for (int off = 1; off < 1024; off <<= 1) {
        unsigned add = (tid >= off) ? sc[tid - off] : 0u;
        unsigned v = sc[tid];
        __syncthreads();
        sc[tid] = v + add;
        __syncthreads();
      }
      unsigned incl = sc[tid];
      unsigned total = sc[1023];
      unsigned excl = incl - pred;
      if (pred && (base + excl) < need)
        out[c2 + base + excl] =
            (unsigned long long)(0x1FFFFFu ^ (levtag | (unsigned)i));
      __syncthreads();
      base += total;
    }
    done = true;
  }

  if (!done) {
    // pathological eq overflow: exact byte-radix reselect (rewrites out[0..k))
    unsigned* hist = sc;
    unsigned* equ = (unsigned*)eqb;
    unsigned prefix = 0, r = k;
    for (int pass = 3; pass >= 0; --pass) {
      int shift = pass * 8;
      for (int i = tid; i < 256; i += 1024) hist[i] = 0;
      __syncthreads();
      for (int i = tid; i < n; i += 1024) {
        float v = s[i];
        unsigned kb = (v > SCORE_THR) ? __float_as_uint(v) : 0u;
        bool match = (pass == 3) || (((kb ^ prefix) >> (shift + 8)) == 0u);
        if (match) atomicAdd(&hist[(kb >> shift) & 255u], 1u);
      }
      __syncthreads();
      if (tid == 0) {
        unsigned cum = 0, byte = 0, rr = r;
        for (int bb = 255; bb >= 0; --bb) {
          unsigned hh = hist[bb];
          if (cum + hh >= r) { byte = (unsigned)bb; rr = r - cum; break; }
          cum += hh;
        }
        sh_byte = byte; sh_r = rr;
      }
      __syncthreads();
      prefix |= (sh_byte << shift);
      r = sh_r;
      __syncthreads();
    }
    unsigned Kstar = prefix;
    if (tid == 0) { sh_cnt = 0; sh_eq = 0; }
    __syncthreads();
    for (int i = tid; i < n; i += 1024) {
      float v = s[i];
      unsigned kb = (v > SCORE_THR) ? __float_as_uint(v) : 0u;
      if (kb > Kstar) {
        unsigned slot = atomicAdd(&sh_cnt, 1u);
        out[slot] = mk_key(kb, lev, (unsigned)i);
      } else if (kb == Kstar) {
        unsigned es = atomicAdd(&sh_eq, 1u);
        if (es < 4096u) equ[es] = (unsigned)i;
      }
    }
    __syncthreads();
    unsigned m = sh_cnt;
    unsigned e2 = (sh_eq < 4096u) ? sh_eq : 4096u;
    unsigned need2 = k - m;
    if (e2 > need2) {
      unsigned P = 1; while (P < e2) P <<= 1;
      for (unsigned t = tid; t < P; t += 1024) if (t >= e2) equ[t] = 0xFFFFFFFFu;
      __syncthreads();
      for (unsigned sz = 2; sz <= P; sz <<= 1)
        for (unsigned st = sz >> 1; st; st >>= 1) {
          for (unsigned w = tid; w < P / 2; w += 1024) {
            unsigned i = ((w & ~(st - 1)) << 1) | (w & (st - 1));
            unsigned l = i | st;
            bool up = ((i & sz) == 0);
            unsigned A = equ[i], B = equ[l];
            if ((A > B) == up) { equ[i] = B; equ[l] = A; }  // ascending
          }
          __syncthreads();
        }
    }
    __syncthreads();
    for (unsigned t = tid; t < need2; t += 1024)
      out[m + t] = ((unsigned long long)Kstar << 21) |
                   (unsigned long long)(0x1FFFFFu ^ (levtag | equ[t]));
  }
}

// ---------------- K4: fused rank (wave-uniform global j-loop) + decode -----------
__global__ __launch_bounds__(256) void k_rankdec(
    const unsigned long long* __restrict__ selkeys,
    const float* __restrict__ g0, const float* __restrict__ g1,
    const float* __restrict__ g2, const float* __restrict__ g3,
    const float* __restrict__ g4, const float* __restrict__ g5,
    float* __restrict__ boxes, float* __restrict__ oscore,
    unsigned char* __restrict__ lab8, unsigned* __restrict__ obmax_u,
    float* __restrict__ outp)
{
  int b = blockIdx.x / ICH2, ic = blockIdx.x % ICH2;
  int tid = threadIdx.x;
  int i = ic * 256 + tid;
  __shared__ double ba[6][6][4];
  if (tid < 36) {
    int lev = tid / 6, a = tid % 6;
    double base = (double)cMIN[lev];
    double scl = (a == 1) ? sqrt((double)cMAX[lev] / (double)cMIN[lev]) : 1.0;
    double hr = sqrt(cRATIO[a]);
    double wr = 1.0 / hr;
    double wsz = base * scl * wr;
    double hsz = base * scl * hr;
    double cc = (double)cSTRIDE[lev] / 2.0;
    ba[lev][a][0] = cc - 0.5 * wsz;
    ba[lev][a][1] = cc - 0.5 * hsz;
    ba[lev][a][2] = cc + 0.5 * wsz;
    ba[lev][a][3] = cc + 0.5 * hsz;
  }

  // ---- rank: j-loop over all keys with wave-uniform addresses (SMEM/L1 path) ----
  const unsigned long long* keys = selkeys + (size_t)b * KTOT;
  unsigned long long mk = (i < KTOT) ? keys[i] : 0ull;
  unsigned r = 0;
  {
    const ulonglong2* k2 = (const ulonglong2*)keys;
    #pragma unroll 8
    for (int j = 0; j < KTOT / 2; ++j) {
      ulonglong2 kk = k2[j];       // thread-invariant address -> scalar load
      r += (kk.x > mk) ? 1u : 0u;
      r += (kk.y > mk) ? 1u : 0u;
    }
  }
  __syncthreads();

  float lmax = 0.f;
  if (i < KTOT) {
    unsigned tag = 0x1FFFFFu ^ (unsigned)(mk & 0x1FFFFFull);
    int lev = tag >> 18;
    int fi = tag & 0x3FFFF;
    unsigned vb2 = (unsigned)(mk >> 21);
    int valid = (vb2 != 0u);
    float score = valid ? __uint_as_float(vb2) : 0.f;
    int label = fi % 80;
    int arow = fi / 80;
    int a = arow % 6, cell = arow / 6;
    int f = cFEAT[lev], ff = f * f;
    int x = cell % f, y = cell / f;
    const float* gb = (lev==0)?g0:(lev==1)?g1:(lev==2)?g2:(lev==3)?g3:(lev==4)?g4:g5;
    const float* pb = gb + (size_t)(b * 24 + a * 4) * ff + y * f + x;
    float d0 = pb[0] * 0.1f, d1 = pb[ff] * 0.1f;
    float d2 = pb[2 * ff] * 0.2f, d3 = pb[3 * ff] * 0.2f;
    const float MR = (float)4.135166556742356;
    d2 = fminf(fmaxf(d2, -MR), MR);
    d3 = fminf(fmaxf(d3, -MR), MR);
    double shx = (double)(x * cSTRIDE[lev]);
    double shy = (double)(y * cSTRIDE[lev]);
    float p0 = (float)(ba[lev][a][0] + shx);
    float p1 = (float)(ba[lev][a][1] + shy);
    float p2 = (float)(ba[lev][a][2] + shx);
    float p3 = (float)(ba[lev][a][3] + shy);
    float pxc = (p0 + p2) * 0.5f, pyc = (p1 + p3) * 0.5f;
    float pw = p2 - p0, ph = p3 - p1;
    float gx = pxc + pw * d0, gy = pyc + ph * d1;
    float gw = pw * expf(d2), gh = ph * expf(d3);
    float x1 = gx - 0.5f * gw, y1 = gy - 0.5f * gh;
    float x2 = gx + 0.5f * gw, y2 = gy + 0.5f * gh;
    x1 = fminf(fmaxf(x1, 0.f), 320.f);
    y1 = fminf(fmaxf(y1, 0.f), 320.f);
    x2 = fminf(fmaxf(x2, 0.f), 320.f);
    y2 = fminf(fmaxf(y2, 0.f), 320.f);
    size_t o = (size_t)b * KTOT + (size_t)r;
    boxes[o * 4 + 0] = x1; boxes[o * 4 + 1] = y1;
    boxes[o * 4 + 2] = x2; boxes[o * 4 + 3] = y2;
    oscore[o] = score;
    lab8[o] = valid ? (unsigned char)label : (unsigned char)0xFF;
    outp[(size_t)NB * KTOT * 5 + o] = (float)label;
    if (!valid) {
      float* det = outp + o * 5;
      det[0] = 0.f; det[1] = 0.f; det[2] = 0.f; det[3] = 0.f; det[4] = 0.f;
      outp[(size_t)NB * KTOT * 6 + o] = 0.f;
    }
    lmax = fmaxf(fmaxf(x1, y1), fmaxf(x2, y2));
  }
  #pragma unroll
  for (int m = 32; m; m >>= 1) lmax = fmaxf(lmax, __shfl_xor(lmax, m));
  if ((tid & 63) == 0) atomicMax(&obmax_u[b], __float_as_uint(lmax));
}

// ---------------- K5: mask-matrix NMS, one block per (image,class) ---------------
__global__ __launch_bounds__(256) void k_nms(
    const float* __restrict__ boxes, const float* __restrict__ oscore,
    const unsigned char* __restrict__ lab8, const unsigned* __restrict__ obmax_u,
    float* __restrict__ out)
{
  int blk = blockIdx.x;
  int b = blk / 80, cls = blk % 80;
  int tid = threadIdx.x;
  int lane = tid & 63, w = tid >> 6;

  __shared__ unsigned short list[NMSCAP];
  __shared__ float ox1[NMSCAP], oy1[NMSCAP], ox2[NMSCAP], oy2[NMSCAP];
  __shared__ float oar[NMSCAP], osc[NMSCAP];
  __shared__ float rx1[NMSCAP], ry1[NMSCAP], rx2[NMSCAP], ry2[NMSCAP];
  __shared__ unsigned long long mask[NMSCAP][8];
  __shared__ unsigned ccnt[24], cbase[24];
  __shared__ int sh_n;
  __shared__ unsigned long long alive_s[8];

  float ofs = (float)cls * (__uint_as_float(obmax_u[b]) + 1.0f);
  const unsigned* lb32 = (const unsigned*)(lab8 + (size_t)b * KTOT);

  unsigned long long balA[6][4];
  #pragma unroll
  for (int ci = 0; ci < 6; ++ci) {
    int chunk = w + ci * 4;
    unsigned v = 0xFFFFFFFFu;
    if (chunk < 22) {
      int u = chunk * 64 + lane;
      if (u < KTOT / 4) v = lb32[u];
    }
    unsigned long long m0 = __ballot(((v      ) & 0xFFu) == (unsigned)cls);
    unsigned long long m1 = __ballot(((v >>  8) & 0xFFu) == (unsigned)cls);
    unsigned long long m2 = __ballot(((v >> 16) & 0xFFu) == (unsigned)cls);
    unsigned long long m3 = __ballot(((v >> 24) & 0xFFu) == (unsigned)cls);
    balA[ci][0] = m0; balA[ci][1] = m1; balA[ci][2] = m2; balA[ci][3] = m3;
    if (chunk < 22 && lane == 0)
      ccnt[chunk] = (unsigned)(__popcll(m0) + __popcll(m1) + __popcll(m2) + __popcll(m3));
  }
  __syncthreads();
  if (tid == 0) {
    unsigned tot = 0;
    for (int c = 0; c < 22; ++c) { cbase[c] = tot; tot += ccnt[c]; }
    sh_n = (tot < NMSCAP) ? (int)tot : NMSCAP;
  }
  __syncthreads();
  int n = sh_n;
  unsigned long long blt = (lane == 0) ? 0ull : ((~0ull) >> (64 - lane));
  #pragma unroll
  for (int ci = 0; ci < 6; ++ci) {
    int chunk = w + ci * 4;
    if (chunk < 22) {
      unsigned pos = cbase[chunk];
      unsigned below = (unsigned)(__popcll(balA[ci][0] & blt) + __popcll(balA[ci][1] & blt) +
                                  __popcll(balA[ci][2] & blt) + __popcll(balA[ci][3] & blt));
      unsigned within = 0;
      #pragma unroll
      for (int k = 0; k < 4; ++k) {
        if ((balA[ci][k] >> lane) & 1ull) {
          unsigned mypos = pos + below + within;
          if (mypos < NMSCAP) list[mypos] = (unsigned short)(chunk * 256 + lane * 4 + k);
          ++within;
        }
      }
    }
  }
  __syncthreads();

  for (int t = tid; t < n; t += 256) {
    int pos = list[t];
    size_t o = (size_t)b * KTOT + pos;
    float4 bb = *(const float4*)(boxes + o * 4);
    rx1[t] = bb.x; ry1[t] = bb.y; rx2[t] = bb.z; ry2[t] = bb.w;
    float a1 = bb.x + ofs, b1 = bb.y + ofs, a2 = bb.z + ofs, b2 = bb.w + ofs;
    ox1[t] = a1; oy1[t] = b1; ox2[t] = a2; oy2[t] = b2;
    oar[t] = (a2 - a1) * (b2 - b1);
    osc[t] = oscore[o];
  }
  __syncthreads();

  int nw = (n + 63) >> 6;
  for (int i = tid; i < n; i += 256) {
    float ax1 = ox1[i], ay1 = oy1[i], ax2 = ox2[i], ay2 = oy2[i], aar = oar[i];
    int w0 = i >> 6;
    for (int wd = w0; wd < nw; ++wd) {
      unsigned long long m = 0;
      int jbase = wd << 6;
      int jend = n - jbase; if (jend > 64) jend = 64;
      for (int jj = 0; jj < jend; ++jj) {
        int j = jbase + jj;
        if (j > i) {
          float ix1 = fmaxf(ax1, ox1[j]);
          float iy1 = fmaxf(ay1, oy1[j]);
          float ix2 = fminf(ax2, ox2[j]);
          float iy2 = fminf(ay2, oy2[j]);
          float iw = fmaxf(ix2 - ix1, 0.f);
          float ih = fmaxf(iy2 - iy1, 0.f);
          float inter = iw * ih;
          float iou = inter / (aar + oar[j] - inter);
          if (iou > IOU_THR) m |= (1ull << jj);
        }
      }
      mask[i][wd] = m;
    }
  }
  __syncthreads();

  if (w == 0) {
    unsigned long long aw = 0;
    if (lane < nw) {
      int rem = n - (lane << 6);
      aw = (rem >= 64) ? ~0ull : ((1ull << rem) - 1ull);
    }
    for (int i = 0; i < n; ++i) {
      int wi = i >> 6;
      unsigned long long mrow = (lane >= wi && lane < nw) ? mask[i][lane] : 0ull;
      unsigned long long tw = shfl64(aw, wi);
      if ((tw >> (i & 63)) & 1ull) aw &= ~mrow;
    }
    if (lane < 8) alive_s[lane] = aw;
  }
  __syncthreads();

  for (int t = tid; t < n; t += 256) {
    float kf = ((alive_s[t >> 6] >> (t & 63)) & 1ull) ? 1.f : 0.f;
    int pos = list[t];
    size_t o = (size_t)b * KTOT + pos;
    float* det = out + o * 5;
    det[0] = rx1[t] * kf; det[1] = ry1[t] * kf;
    det[2] = rx2[t] * kf; det[3] = ry2[t] * kf;
    det[4] = osc[t] * kf;
    out[(size_t)NB * KTOT * 6 + o] = kf;
  }
}

extern "C" void kernel_launch(void* const* d_in, const int* in_sizes, int n_in,
                              void* d_out, int out_size, void* d_ws, size_t ws_size,
                              hipStream_t stream) {
  (void)in_sizes; (void)n_in; (void)out_size; (void)ws_size;
  const float* cls[6]; const float* bbx[6];
  for (int i = 0; i < 6; ++i) {
    cls[i] = (const float*)d_in[2 * i];
    bbx[i] = (const float*)d_in[2 * i + 1];
  }
  char* ws = (char*)d_ws;
  float* scores = (float*)ws;                                         // 4,139,520
  unsigned long long* selkeys = (unsigned long long*)(ws + 4139520);  // 175,360
  float* boxes  = (float*)(ws + 4314880);                             // 350,720
  float* oscore = (float*)(ws + 4665600);                             // 87,680
  unsigned char* lab8 = (unsigned char*)(ws + 4753280);               // 21,920
  unsigned* obmax_u = (unsigned*)(ws + 5016320);                      // 16 B
  unsigned* ctrl    = (unsigned*)(ws + 5016576);                      // 768 B
  unsigned* bhist   = (unsigned*)(ws + 5017600);                      // 24*256*42*4 = 1,032,192
  unsigned long long* eqg = (unsigned long long*)(ws + 6049792);      // 786,432

  k_softmax<<<NB * 78, 256, 0, stream>>>(cls[0], cls[1], cls[2], cls[3], cls[4], cls[5],
                                         scores, bhist, obmax_u, ctrl);
  k_emit<<<NB * 24, 256, 0, stream>>>(scores, bhist, ctrl, selkeys, eqg);
  k_finalize<<<24, 1024, 0, stream>>>(scores, bhist, ctrl, selkeys, eqg);
  k_rankdec<<<NB * ICH2, 256, 0, stream>>>(selkeys, bbx[0], bbx[1], bbx[2], bbx[3],
                                           bbx[4], bbx[5], boxes, oscore, lab8,
                                           obmax_u, (float*)d_out);
  k_nms<<<NB * 80, 256, 0, stream>>>(boxes, oscore, lab8, obmax_u, (float*)d_out);
}

// Round 14
// 96.172 us; speedup vs baseline: 2.7815x; 2.7815x over previous
//
#include <hip/hip_runtime.h>
#include <stdint.h>

#define NB 4
#define KTOT 5480
#define PER_IMG 258720
#define SCORE_THR 0.02f
#define IOU_THR 0.45f
#define REL_BASE 0x3CA3D70Bu   // smallest float bits > 0.02f
#define JCH 10                 // rank j-chunks
#define JSZ 548                // KTOT / JCH
#define ICH 11                 // rank/decode i-chunks (512 keys each)
#define NMSCAP 512
#define HBINS 256              // coarse hist bins: (kb-REL_BASE)>>18 in [0,182]
#define HPART 42               // max partials per task (lev0)

__constant__ int cFEAT[6]    = {20,10,5,3,2,1};
__constant__ int cSTRIDE[6]  = {16,32,64,107,160,320};
__constant__ int cMIN[6]     = {48,100,150,202,253,304};
__constant__ int cMAX[6]     = {100,150,202,253,304,320};
__constant__ int cNFLAT[6]   = {192000,48000,12000,4320,1920,480};
__constant__ int cFLATOFF[6] = {0,192000,240000,252000,256320,258240};
__constant__ int cKSEL[6]    = {1000,1000,1000,1000,1000,480};
__constant__ int cKOFF[6]    = {0,1000,2000,3000,4000,5000};
__constant__ double cRATIO[6] = {1.0,1.0,0.5,2.0,1.0/3.0,3.0};
// emit entries: 16 lev0 chunks, 4 lev1 chunks, 1 each lev2..5 -> 24 per image
__constant__ int eTLEV[24] = {0,0,0,0,0,0,0,0,0,0,0,0,0,0,0,0, 1,1,1,1, 2,3,4,5};
__constant__ int eTCHK[24] = {0,1,2,3,4,5,6,7,8,9,10,11,12,13,14,15, 0,1,2,3, 0,0,0,0};
__constant__ int eNCH[6]   = {16,4,1,1,1,1};
__constant__ int hL0[6]    = {0,42,54,60,66,72};   // softmax-block range per level
__constant__ int hLN[6]    = {42,12,6,6,6,6};

__device__ __forceinline__ unsigned long long mk_key(unsigned kb, int lev, unsigned idx) {
  return ((unsigned long long)kb << 21) |
         (unsigned long long)(0x1FFFFFu ^ (((unsigned)lev << 18) | idx));
}

__device__ __forceinline__ unsigned long long shfl64(unsigned long long x, int src) {
  int lo = __shfl((int)(unsigned)(x & 0xffffffffull), src);
  int hi = __shfl((int)(unsigned)(x >> 32), src);
  return ((unsigned long long)(unsigned)hi << 32) | (unsigned)lo;
}

// ---------------- K1: tiled softmax + per-block overwrite histogram --------------
// bhist layout is BIN-MAJOR: bhist[(task*HBINS + bin)*HPART + j]; block j of the
// task writes column j (no atomics, no pre-zero; unwritten j never read).
__global__ __launch_bounds__(256) void k_softmax(
    const float* __restrict__ c0, const float* __restrict__ c1,
    const float* __restrict__ c2, const float* __restrict__ c3,
    const float* __restrict__ c4, const float* __restrict__ c5,
    float* __restrict__ scores, unsigned* __restrict__ bhist,
    unsigned* __restrict__ obmax_u, unsigned* __restrict__ ctrl)
{
  int t = blockIdx.x;
  int tid = threadIdx.x;
  if (t == 0) {
    if (tid < 4) obmax_u[tid] = 0u;
    if (tid >= 64 && tid < 256) ctrl[tid - 64] = 0u;
  }
  int b = t / 78, rem = t % 78;
  int lev, a, cb;
  if (rem < 42)      { lev = 0; a = rem / 7;         cb = (rem % 7) * 64; }
  else if (rem < 54) { lev = 1; a = (rem - 42) >> 1; cb = ((rem - 42) & 1) * 64; }
  else               { lev = 2 + (rem - 54) / 6; a = (rem - 54) % 6; cb = 0; }
  const float* cls = (lev==0)?c0:(lev==1)?c1:(lev==2)?c2:(lev==3)?c3:(lev==4)?c4:c5;
  int f = cFEAT[lev], ff = f * f;
  int ncell = ff - cb; if (ncell > 64) ncell = 64;

  __shared__ float tile[81 * 64];
  __shared__ unsigned hcnt[HBINS];
  if (tid < HBINS) hcnt[tid] = 0;
  const float* base = cls + (size_t)(b * 486 + a * 81) * ff + cb;
  for (int t2 = tid; t2 < 81 * 64; t2 += 256) {
    int c = t2 >> 6, cell = t2 & 63;
    if (cell < ncell)
      tile[(c << 6) | (cell ^ (c & 63))] = base[c * ff + cell];
  }
  __syncthreads();

  int lane = tid & 63, w = tid >> 6;
  for (int cell = w; cell < ncell; cell += 4) {
    float v1 = tile[(lane << 6) | (cell ^ lane)];
    float v2 = (lane <= 16) ? tile[((lane + 64) << 6) | (cell ^ lane)]
                            : __uint_as_float(0xff800000u);
    float mx = fmaxf(v1, v2);
    #pragma unroll
    for (int m = 32; m; m >>= 1) mx = fmaxf(mx, __shfl_xor(mx, m));
    float e1 = expf(v1 - mx);
    float e2 = (lane <= 16) ? expf(v2 - mx) : 0.f;
    float sm = e1 + e2;
    #pragma unroll
    for (int m = 32; m; m >>= 1) sm += __shfl_xor(sm, m);
    int row = (cb + cell) * 6 + a;
    float* out = scores + (size_t)b * PER_IMG + cFLATOFF[lev] + row * 80;
    float p1 = e1 / sm;
    out[lane] = (p1 > SCORE_THR) ? p1 : -1.f;
    if (p1 > SCORE_THR)
      atomicAdd(&hcnt[(__float_as_uint(p1) - REL_BASE) >> 18], 1u);
    if (lane < 16) {
      float p2 = e2 / sm;
      out[lane + 64] = (p2 > SCORE_THR) ? p2 : -1.f;
      if (p2 > SCORE_THR)
        atomicAdd(&hcnt[(__float_as_uint(p2) - REL_BASE) >> 18], 1u);
    }
  }
  __syncthreads();
  int task = b * 6 + lev;
  int j = rem - hL0[lev];
  if (tid < HBINS)
    bhist[((size_t)task * HBINS + tid) * HPART + j] = hcnt[tid];
}

// ---------------- K2: chunked emit with inline plan (bin-major hist sum) ---------
__global__ __launch_bounds__(256) void k_emit(
    const float* __restrict__ scores, const unsigned* __restrict__ bhist,
    unsigned* __restrict__ ctrl, unsigned long long* __restrict__ selkeys,
    unsigned long long* __restrict__ eqg)
{
  int b = blockIdx.x / 24, ent = blockIdx.x % 24;
  int lev = eTLEV[ent], chk = eTCHK[ent];
  int task = b * 6 + lev;
  int n = cNFLAT[lev];
  int tid = threadIdx.x;
  const float* s = scores + (size_t)b * PER_IMG + cFLATOFF[lev];
  unsigned long long* out = selkeys + (size_t)b * KTOT + cKOFF[lev];

  if (lev == 5) {  // keep all
    for (int i = tid; i < n; i += 256) {
      float v = s[i];
      unsigned kb = (v > SCORE_THR) ? __float_as_uint(v) : 0u;
      out[i] = mk_key(kb, lev, (unsigned)i);
    }
    return;
  }

  unsigned k = (unsigned)cKSEL[lev];
  __shared__ unsigned long long wbuf[1024];
  __shared__ unsigned long long ebuf[4096];
  __shared__ unsigned sc[256];
  __shared__ unsigned wcnt, ecnt, sbw, sbe, sh_mode, sh_b1;

  // ---- inline plan: bin-major sum (contiguous), suffix-scan 256 bins ----
  {
    const unsigned* hb = bhist + ((size_t)task * HBINS + tid) * HPART;
    int np = hLN[lev];
    unsigned cnt = 0;
    for (int j = 0; j < np; ++j) cnt += hb[j];   // contiguous: ~3 cache lines
    sc[tid] = cnt;
    __syncthreads();
    for (int off = 1; off < 256; off <<= 1) {
      unsigned cur = sc[tid];
      unsigned add = (tid + off < 256) ? sc[tid + off] : 0u;
      __syncthreads();
      sc[tid] = cur + add;
      __syncthreads();
    }
    unsigned c = sc[0];
    if (tid == 0 && c < k) sh_mode = 1u;
    if (c >= k) {
      unsigned above = (tid == 255) ? 0u : sc[tid + 1];
      if (above < k && above + cnt >= k) { sh_mode = 0u; sh_b1 = (unsigned)tid; }
    }
    if (tid == 0) { wcnt = 0; ecnt = 0; }
    __syncthreads();
  }
  unsigned mode = sh_mode;

  int csz = n / eNCH[lev];
  int start = chk * csz;
  const float4* s4 = (const float4*)(s + start);
  int n4 = csz >> 2;

  if (mode == 0u) {
    unsigned b1 = sh_b1;
    unsigned base_lo = REL_BASE + (b1 << 18);
    unsigned base_hi = base_lo + (1u << 18);
    #pragma unroll 4
    for (int i0 = tid; i0 < n4; i0 += 256) {
      float4 vv = s4[i0];
      #pragma unroll
      for (int e2 = 0; e2 < 4; ++e2) {
        float v = (e2==0)?vv.x:(e2==1)?vv.y:(e2==2)?vv.z:vv.w;
        if (v > SCORE_THR) {
          unsigned kb = __float_as_uint(v);
          unsigned idx = (unsigned)(start + i0 * 4 + e2);
          if (kb >= base_hi) {
            unsigned p = atomicAdd(&wcnt, 1u);
            if (p < 1024u) wbuf[p] = mk_key(kb, lev, idx);
          } else if (kb >= base_lo) {
            unsigned p = atomicAdd(&ecnt, 1u);
            if (p < 4096u) ebuf[p] = mk_key(kb, lev, idx);
          }
        }
      }
    }
  } else {  // mode 1: all candidates are winners (c < k)
    #pragma unroll 4
    for (int i0 = tid; i0 < n4; i0 += 256) {
      float4 vv = s4[i0];
      #pragma unroll
      for (int e2 = 0; e2 < 4; ++e2) {
        float v = (e2==0)?vv.x:(e2==1)?vv.y:(e2==2)?vv.z:vv.w;
        if (v > SCORE_THR) {
          unsigned p = atomicAdd(&wcnt, 1u);
          if (p < 1024u) wbuf[p] = mk_key(__float_as_uint(v), lev,
                                          (unsigned)(start + i0 * 4 + e2));
        }
      }
    }
  }
  __syncthreads();
  if (tid == 0) {
    sbw = atomicAdd(&ctrl[task * 8 + 2], wcnt);
    sbe = atomicAdd(&ctrl[task * 8 + 3], ecnt);
  }
  __syncthreads();
  unsigned nw = (wcnt < 1024u) ? wcnt : 1024u;
  unsigned ne = (ecnt < 4096u) ? ecnt : 4096u;
  unsigned bw = sbw, be = sbe;
  for (unsigned t = tid; t < nw; t += 256) out[bw + t] = wbuf[t];
  for (unsigned t = tid; t < ne; t += 256) {
    unsigned g = be + t;
    if (g < 4096u) eqg[(size_t)task * 4096 + g] = ebuf[t];
  }
}

// ---------------- K3: finalize (ties / fillers / pathological radix) -------------
__global__ __launch_bounds__(1024) void k_finalize(
    const float* __restrict__ scores, const unsigned* __restrict__ bhist,
    const unsigned* __restrict__ ctrl, unsigned long long* __restrict__ selkeys,
    const unsigned long long* __restrict__ eqg)
{
  int task = blockIdx.x;
  int b = task / 6, lev = task % 6;
  if (lev == 5) return;
  int tid = threadIdx.x;
  unsigned k = (unsigned)cKSEL[lev];
  int n = cNFLAT[lev];
  const float* s = scores + (size_t)b * PER_IMG + cFLATOFF[lev];
  unsigned long long* out = selkeys + (size_t)b * KTOT + cKOFF[lev];
  unsigned levtag = (unsigned)lev << 18;

  __shared__ unsigned long long eqb[4096];
  __shared__ unsigned sc[1024];
  __shared__ unsigned sh_cnt, sh_eq, sh_byte, sh_r;

  // ---- recompute candidate count from bin-major partials ----
  unsigned hval = 0;
  if (tid < HBINS) {
    const unsigned* hb = bhist + ((size_t)task * HBINS + tid) * HPART;
    int np = hLN[lev];
    for (int j = 0; j < np; ++j) hval += hb[j];
  }
  sc[tid] = (tid < HBINS) ? hval : 0u;
  __syncthreads();
  for (int off = 128; off >= 1; off >>= 1) {
    if (tid < off) sc[tid] += sc[tid + off];
    __syncthreads();
  }
  unsigned c = sc[0];
  __syncthreads();
  unsigned mode = (c >= k) ? 0u : 1u;
  bool done = false;

  if (mode == 0u) {
    unsigned cnt = ctrl[task * 8 + 2];
    unsigned e = ctrl[task * 8 + 3];
    unsigned need = k - cnt;
    if (e <= 4096u) {
      const unsigned long long* eq = eqg + (size_t)task * 4096;
      if (e == need) {
        for (unsigned t = tid; t < need; t += 1024) out[cnt + t] = eq[t];
      } else {
        unsigned P = 1; while (P < e) P <<= 1;
        for (unsigned t = tid; t < P; t += 1024) eqb[t] = (t < e) ? eq[t] : 0ull;
        __syncthreads();
        for (unsigned sz = 2; sz <= P; sz <<= 1)
          for (unsigned st = sz >> 1; st; st >>= 1) {
            for (unsigned w = tid; w < P / 2; w += 1024) {
              unsigned i = ((w & ~(st - 1)) << 1) | (w & (st - 1));
              unsigned l = i | st;
              bool up = ((i & sz) == 0);
              unsigned long long A = eqb[i], B = eqb[l];
              if ((A < B) == up) { eqb[i] = B; eqb[l] = A; }  // descending
            }
            __syncthreads();
          }
        for (unsigned t = tid; t < need; t += 1024) out[cnt + t] = eqb[t];
      }
      done = true;
    }
  } else {
    // mode 1: candidates already emitted; append (k-c) smallest-index fillers
    unsigned c2 = ctrl[task * 8 + 2];
    unsigned need = k - c2;
    unsigned base = 0;
    for (int start = 0; start < n && base < need; start += 1024) {
      int i = start + tid;
      unsigned pred = (i < n && !(s[i] > SCORE_THR)) ? 1u : 0u;
      sc[tid] = pred;
      __syncthreads();
      for (int off = 1; off < 1024; off <<= 1) {
        unsigned add = (tid >= off) ? sc[tid - off] : 0u;
        unsigned v = sc[tid];
        __syncthreads();
        sc[tid] = v + add;
        __syncthreads();
      }
      unsigned incl = sc[tid];
      unsigned total = sc[1023];
      unsigned excl = incl - pred;
      if (pred && (base + excl) < need)
        out[c2 + base + excl] =
            (unsigned long long)(0x1FFFFFu ^ (levtag | (unsigned)i));
      __syncthreads();
      base += total;
    }
    done = true;
  }

  if (!done) {
    // pathological eq overflow: exact byte-radix reselect (rewrites out[0..k))
    unsigned* hist = sc;
    unsigned* equ = (unsigned*)eqb;
    unsigned prefix = 0, r = k;
    for (int pass = 3; pass >= 0; --pass) {
      int shift = pass * 8;
      for (int i = tid; i < 256; i += 1024) hist[i] = 0;
      __syncthreads();
      for (int i = tid; i < n; i += 1024) {
        float v = s[i];
        unsigned kb = (v > SCORE_THR) ? __float_as_uint(v) : 0u;
        bool match = (pass == 3) || (((kb ^ prefix) >> (shift + 8)) == 0u);
        if (match) atomicAdd(&hist[(kb >> shift) & 255u], 1u);
      }
      __syncthreads();
      if (tid == 0) {
        unsigned cum = 0, byte = 0, rr = r;
        for (int bb = 255; bb >= 0; --bb) {
          unsigned hh = hist[bb];
          if (cum + hh >= r) { byte = (unsigned)bb; rr = r - cum; break; }
          cum += hh;
        }
        sh_byte = byte; sh_r = rr;
      }
      __syncthreads();
      prefix |= (sh_byte << shift);
      r = sh_r;
      __syncthreads();
    }
    unsigned Kstar = prefix;
    if (tid == 0) { sh_cnt = 0; sh_eq = 0; }
    __syncthreads();
    for (int i = tid; i < n; i += 1024) {
      float v = s[i];
      unsigned kb = (v > SCORE_THR) ? __float_as_uint(v) : 0u;
      if (kb > Kstar) {
        unsigned slot = atomicAdd(&sh_cnt, 1u);
        out[slot] = mk_key(kb, lev, (unsigned)i);
      } else if (kb == Kstar) {
        unsigned es = atomicAdd(&sh_eq, 1u);
        if (es < 4096u) equ[es] = (unsigned)i;
      }
    }
    __syncthreads();
    unsigned m = sh_cnt;
    unsigned e2 = (sh_eq < 4096u) ? sh_eq : 4096u;
    unsigned need2 = k - m;
    if (e2 > need2) {
      unsigned P = 1; while (P < e2) P <<= 1;
      for (unsigned t = tid; t < P; t += 1024) if (t >= e2) equ[t] = 0xFFFFFFFFu;
      __syncthreads();
      for (unsigned sz = 2; sz <= P; sz <<= 1)
        for (unsigned st = sz >> 1; st; st >>= 1) {
          for (unsigned w = tid; w < P / 2; w += 1024) {
            unsigned i = ((w & ~(st - 1)) << 1) | (w & (st - 1));
            unsigned l = i | st;
            bool up = ((i & sz) == 0);
            unsigned A = equ[i], B = equ[l];
            if ((A > B) == up) { equ[i] = B; equ[l] = A; }  // ascending
          }
          __syncthreads();
        }
    }
    __syncthreads();
    for (unsigned t = tid; t < need2; t += 1024)
      out[m + t] = ((unsigned long long)Kstar << 21) |
                   (unsigned long long)(0x1FFFFFu ^ (levtag | equ[t]));
  }
}

// ---------------- K4a: partitioned O(N^2) rank (fence-free, LDS broadcast) -------
__global__ __launch_bounds__(512) void k_rank(
    const unsigned long long* __restrict__ selkeys, unsigned* __restrict__ rank_part)
{
  int blk = blockIdx.x;
  int jc = blk % JCH;
  int rest = blk / JCH;
  int ic = rest % ICH, b = rest / ICH;
  int tid = threadIdx.x;
  __shared__ __align__(16) unsigned long long sk[JSZ];
  const unsigned long long* keys = selkeys + (size_t)b * KTOT;
  for (int j = tid; j < JSZ; j += 512) sk[j] = keys[jc * JSZ + j];
  int i = ic * 512 + tid;
  unsigned long long mk = (i < KTOT) ? keys[i] : 0ull;
  __syncthreads();
  unsigned r = 0;
  const ulonglong2* sk2 = (const ulonglong2*)sk;
  #pragma unroll 8
  for (int j = 0; j < JSZ / 2; ++j) {
    ulonglong2 kk = sk2[j];
    r += (kk.x > mk) ? 1u : 0u;
    r += (kk.y > mk) ? 1u : 0u;
  }
  if (i < KTOT) rank_part[((size_t)jc * NB + b) * KTOT + i] = r;
}

// ---------------- K4b: sum partials + decode + scatter ---------------------------
__global__ __launch_bounds__(512) void k_decode(
    const unsigned long long* __restrict__ selkeys, const unsigned* __restrict__ rank_part,
    const float* __restrict__ g0, const float* __restrict__ g1,
    const float* __restrict__ g2, const float* __restrict__ g3,
    const float* __restrict__ g4, const float* __restrict__ g5,
    float* __restrict__ boxes, float* __restrict__ oscore,
    unsigned char* __restrict__ lab8, unsigned* __restrict__ obmax_u,
    float* __restrict__ outp)
{
  int b = blockIdx.x / ICH, ic = blockIdx.x % ICH;
  int tid = threadIdx.x;
  int i = ic * 512 + tid;
  __shared__ double ba[6][6][4];
  if (tid < 36) {
    int lev = tid / 6, a = tid % 6;
    double base = (double)cMIN[lev];
    double scl = (a == 1) ? sqrt((double)cMAX[lev] / (double)cMIN[lev]) : 1.0;
    double hr = sqrt(cRATIO[a]);
    double wr = 1.0 / hr;
    double wsz = base * scl * wr;
    double hsz = base * scl * hr;
    double cc = (double)cSTRIDE[lev] / 2.0;
    ba[lev][a][0] = cc - 0.5 * wsz;
    ba[lev][a][1] = cc - 0.5 * hsz;
    ba[lev][a][2] = cc + 0.5 * wsz;
    ba[lev][a][3] = cc + 0.5 * hsz;
  }
  __syncthreads();

  float lmax = 0.f;
  if (i < KTOT) {
    unsigned long long mk = selkeys[(size_t)b * KTOT + i];
    unsigned r = 0;
    #pragma unroll
    for (int jc = 0; jc < JCH; ++jc)
      r += rank_part[((size_t)jc * NB + b) * KTOT + i];
    unsigned tag = 0x1FFFFFu ^ (unsigned)(mk & 0x1FFFFFull);
    int lev = tag >> 18;
    int fi = tag & 0x3FFFF;
    unsigned vb2 = (unsigned)(mk >> 21);
    int valid = (vb2 != 0u);
    float score = valid ? __uint_as_float(vb2) : 0.f;
    int label = fi % 80;
    int arow = fi / 80;
    int a = arow % 6, cell = arow / 6;
    int f = cFEAT[lev], ff = f * f;
    int x = cell % f, y = cell / f;
    const float* gb = (lev==0)?g0:(lev==1)?g1:(lev==2)?g2:(lev==3)?g3:(lev==4)?g4:g5;
    const float* pb = gb + (size_t)(b * 24 + a * 4) * ff + y * f + x;
    float d0 = pb[0] * 0.1f, d1 = pb[ff] * 0.1f;
    float d2 = pb[2 * ff] * 0.2f, d3 = pb[3 * ff] * 0.2f;
    const float MR = (float)4.135166556742356;
    d2 = fminf(fmaxf(d2, -MR), MR);
    d3 = fminf(fmaxf(d3, -MR), MR);
    double shx = (double)(x * cSTRIDE[lev]);
    double shy = (double)(y * cSTRIDE[lev]);
    float p0 = (float)(ba[lev][a][0] + shx);
    float p1 = (float)(ba[lev][a][1] + shy);
    float p2 = (float)(ba[lev][a][2] + shx);
    float p3 = (float)(ba[lev][a][3] + shy);
    float pxc = (p0 + p2) * 0.5f, pyc = (p1 + p3) * 0.5f;
    float pw = p2 - p0, ph = p3 - p1;
    float gx = pxc + pw * d0, gy = pyc + ph * d1;
    float gw = pw * expf(d2), gh = ph * expf(d3);
    float x1 = gx - 0.5f * gw, y1 = gy - 0.5f * gh;
    float x2 = gx + 0.5f * gw, y2 = gy + 0.5f * gh;
    x1 = fminf(fmaxf(x1, 0.f), 320.f);
    y1 = fminf(fmaxf(y1, 0.f), 320.f);
    x2 = fminf(fmaxf(x2, 0.f), 320.f);
    y2 = fminf(fmaxf(y2, 0.f), 320.f);
    size_t o = (size_t)b * KTOT + (size_t)r;
    boxes[o * 4 + 0] = x1; boxes[o * 4 + 1] = y1;
    boxes[o * 4 + 2] = x2; boxes[o * 4 + 3] = y2;
    oscore[o] = score;
    lab8[o] = valid ? (unsigned char)label : (unsigned char)0xFF;
    outp[(size_t)NB * KTOT * 5 + o] = (float)label;
    if (!valid) {
      float* det = outp + o * 5;
      det[0] = 0.f; det[1] = 0.f; det[2] = 0.f; det[3] = 0.f; det[4] = 0.f;
      outp[(size_t)NB * KTOT * 6 + o] = 0.f;
    }
    lmax = fmaxf(fmaxf(x1, y1), fmaxf(x2, y2));
  }
  #pragma unroll
  for (int m = 32; m; m >>= 1) lmax = fmaxf(lmax, __shfl_xor(lmax, m));
  if ((tid & 63) == 0) atomicMax(&obmax_u[b], __float_as_uint(lmax));
}

// ---------------- K5: mask-matrix NMS, one block per (image,class) ---------------
__global__ __launch_bounds__(256) void k_nms(
    const float* __restrict__ boxes, const float* __restrict__ oscore,
    const unsigned char* __restrict__ lab8, const unsigned* __restrict__ obmax_u,
    float* __restrict__ out)
{
  int blk = blockIdx.x;
  int b = blk / 80, cls = blk % 80;
  int tid = threadIdx.x;
  int lane = tid & 63, w = tid >> 6;

  __shared__ unsigned short list[NMSCAP];
  __shared__ float ox1[NMSCAP], oy1[NMSCAP], ox2[NMSCAP], oy2[NMSCAP];
  __shared__ float oar[NMSCAP], osc[NMSCAP];
  __shared__ float rx1[NMSCAP], ry1[NMSCAP], rx2[NMSCAP], ry2[NMSCAP];
  __shared__ unsigned long long mask[NMSCAP][8];
  __shared__ unsigned ccnt[24], cbase[24];
  __shared__ int sh_n;
  __shared__ unsigned long long alive_s[8];

  float ofs = (float)cls * (__uint_as_float(obmax_u[b]) + 1.0f);
  const unsigned* lb32 = (const unsigned*)(lab8 + (size_t)b * KTOT);

  unsigned long long balA[6][4];
  #pragma unroll
  for (int ci = 0; ci < 6; ++ci) {
    int chunk = w + ci * 4;
    unsigned v = 0xFFFFFFFFu;
    if (chunk < 22) {
      int u = chunk * 64 + lane;
      if (u < KTOT / 4) v = lb32[u];
    }
    unsigned long long m0 = __ballot(((v      ) & 0xFFu) == (unsigned)cls);
    unsigned long long m1 = __ballot(((v >>  8) & 0xFFu) == (unsigned)cls);
    unsigned long long m2 = __ballot(((v >> 16) & 0xFFu) == (unsigned)cls);
    unsigned long long m3 = __ballot(((v >> 24) & 0xFFu) == (unsigned)cls);
    balA[ci][0] = m0; balA[ci][1] = m1; balA[ci][2] = m2; balA[ci][3] = m3;
    if (chunk < 22 && lane == 0)
      ccnt[chunk] = (unsigned)(__popcll(m0) + __popcll(m1) + __popcll(m2) + __popcll(m3));
  }
  __syncthreads();
  if (tid == 0) {
    unsigned tot = 0;
    for (int c = 0; c < 22; ++c) { cbase[c] = tot; tot += ccnt[c]; }
    sh_n = (tot < NMSCAP) ? (int)tot : NMSCAP;
  }
  __syncthreads();
  int n = sh_n;
  unsigned long long blt = (lane == 0) ? 0ull : ((~0ull) >> (64 - lane));
  #pragma unroll
  for (int ci = 0; ci < 6; ++ci) {
    int chunk = w + ci * 4;
    if (chunk < 22) {
      unsigned pos = cbase[chunk];
      unsigned below = (unsigned)(__popcll(balA[ci][0] & blt) + __popcll(balA[ci][1] & blt) +
                                  __popcll(balA[ci][2] & blt) + __popcll(balA[ci][3] & blt));
      unsigned within = 0;
      #pragma unroll
      for (int k = 0; k < 4; ++k) {
        if ((balA[ci][k] >> lane) & 1ull) {
          unsigned mypos = pos + below + within;
          if (mypos < NMSCAP) list[mypos] = (unsigned short)(chunk * 256 + lane * 4 + k);
          ++within;
        }
      }
    }
  }
  __syncthreads();

  for (int t = tid; t < n; t += 256) {
    int pos = list[t];
    size_t o = (size_t)b * KTOT + pos;
    float4 bb = *(const float4*)(boxes + o * 4);
    rx1[t] = bb.x; ry1[t] = bb.y; rx2[t] = bb.z; ry2[t] = bb.w;
    float a1 = bb.x + ofs, b1 = bb.y + ofs, a2 = bb.z + ofs, b2 = bb.w + ofs;
    ox1[t] = a1; oy1[t] = b1; ox2[t] = a2; oy2[t] = b2;
    oar[t] = (a2 - a1) * (b2 - b1);
    osc[t] = oscore[o];
  }
  __syncthreads();

  int nw = (n + 63) >> 6;
  for (int i = tid; i < n; i += 256) {
    float ax1 = ox1[i], ay1 = oy1[i], ax2 = ox2[i], ay2 = oy2[i], aar = oar[i];
    int w0 = i >> 6;
    for (int wd = w0; wd < nw; ++wd) {
      unsigned long long m = 0;
      int jbase = wd << 6;
      int jend = n - jbase; if (jend > 64) jend = 64;
      for (int jj = 0; jj < jend; ++jj) {
        int j = jbase + jj;
        if (j > i) {
          float ix1 = fmaxf(ax1, ox1[j]);
          float iy1 = fmaxf(ay1, oy1[j]);
          float ix2 = fminf(ax2, ox2[j]);
          float iy2 = fminf(ay2, oy2[j]);
          float iw = fmaxf(ix2 - ix1, 0.f);
          float ih = fmaxf(iy2 - iy1, 0.f);
          float inter = iw * ih;
          float iou = inter / (aar + oar[j] - inter);
          if (iou > IOU_THR) m |= (1ull << jj);
        }
      }
      mask[i][wd] = m;
    }
  }
  __syncthreads();

  if (w == 0) {
    unsigned long long aw = 0;
    if (lane < nw) {
      int rem = n - (lane << 6);
      aw = (rem >= 64) ? ~0ull : ((1ull << rem) - 1ull);
    }
    for (int i = 0; i < n; ++i) {
      int wi = i >> 6;
      unsigned long long mrow = (lane >= wi && lane < nw) ? mask[i][lane] : 0ull;
      unsigned long long tw = shfl64(aw, wi);
      if ((tw >> (i & 63)) & 1ull) aw &= ~mrow;
    }
    if (lane < 8) alive_s[lane] = aw;
  }
  __syncthreads();

  for (int t = tid; t < n; t += 256) {
    float kf = ((alive_s[t >> 6] >> (t & 63)) & 1ull) ? 1.f : 0.f;
    int pos = list[t];
    size_t o = (size_t)b * KTOT + pos;
    float* det = out + o * 5;
    det[0] = rx1[t] * kf; det[1] = ry1[t] * kf;
    det[2] = rx2[t] * kf; det[3] = ry2[t] * kf;
    det[4] = osc[t] * kf;
    out[(size_t)NB * KTOT * 6 + o] = kf;
  }
}

extern "C" void kernel_launch(void* const* d_in, const int* in_sizes, int n_in,
                              void* d_out, int out_size, void* d_ws, size_t ws_size,
                              hipStream_t stream) {
  (void)in_sizes; (void)n_in; (void)out_size; (void)ws_size;
  const float* cls[6]; const float* bbx[6];
  for (int i = 0; i < 6; ++i) {
    cls[i] = (const float*)d_in[2 * i];
    bbx[i] = (const float*)d_in[2 * i + 1];
  }
  char* ws = (char*)d_ws;
  float* scores = (float*)ws;                                         // 4,139,520
  unsigned* rank_part = (unsigned*)ws;                                // aliases scores (dead after finalize)
  unsigned long long* selkeys = (unsigned long long*)(ws + 4139520);  // 175,360
  float* boxes  = (float*)(ws + 4314880);                             // 350,720
  float* oscore = (float*)(ws + 4665600);                             // 87,680
  unsigned char* lab8 = (unsigned char*)(ws + 4753280);               // 21,920
  unsigned* obmax_u = (unsigned*)(ws + 5016320);                      // 16 B
  unsigned* ctrl    = (unsigned*)(ws + 5016576);                      // 768 B
  unsigned* bhist   = (unsigned*)(ws + 5017600);                      // 24*256*42*4 = 1,032,192
  unsigned long long* eqg = (unsigned long long*)(ws + 6049792);      // 786,432

  k_softmax<<<NB * 78, 256, 0, stream>>>(cls[0], cls[1], cls[2], cls[3], cls[4], cls[5],
                                         scores, bhist, obmax_u, ctrl);
  k_emit<<<NB * 24, 256, 0, stream>>>(scores, bhist, ctrl, selkeys, eqg);
  k_finalize<<<24, 1024, 0, stream>>>(scores, bhist, ctrl, selkeys, eqg);
  k_rank<<<NB * ICH * JCH, 512, 0, stream>>>(selkeys, rank_part);
  k_decode<<<NB * ICH, 512, 0, stream>>>(selkeys, rank_part, bbx[0], bbx[1], bbx[2],
                                         bbx[3], bbx[4], bbx[5], boxes, oscore, lab8,
                                         obmax_u, (float*)d_out);
  k_nms<<<NB * 80, 256, 0, stream>>>(boxes, oscore, lab8, obmax_u, (float*)d_out);
}